// Round 16
// baseline (1519.041 us; speedup 1.0000x reference)
//
#include <hip/hip_runtime.h>
#include <hip/hip_bf16.h>

// ---------------------------------------------------------------------------
// LSTM_37847251812594: 2-layer LSTM (B=256, T=64, n_x=512, n_h=1024) + FC+softmax
// Round 16: K-split wave pairs — halve the 16x-redundant LDS A-read traffic.
//   - 16 waves = 8 m-pairs x 2 K-halves. Wave (p, kh): m-groups {2p,2p+1};
//     kh=0 -> h-recurrent chunks (32, with bias), kh=1 -> x chunks (NX, zero).
//     Per CU: LDS A-reads 2MB -> 1MB, B-reads/MFMA/waves unchanged.
//   - partial sums reduced via 32KB LDS buffer [p][val][lane] (lane-contig,
//     conflict-free); kh=0 waves then run r10's verified shfl-xor epilogue.
//   - LDS = 128KB weights + 32KB reduce = 160KB (1 block/CU as before).
//   - everything else = r14 (best at 1435): layer-split, frag-major h/x,
//     k-rotation, two-level grid barrier, unroll-8 I$-safe loop.
// ---------------------------------------------------------------------------

typedef short  bf16x8 __attribute__((ext_vector_type(8)));
typedef float  f32x4  __attribute__((ext_vector_type(4)));

#define NHID   1024
#define NBATCH 256
#define NBLK   256
#define HSZE   (NBATCH * NHID)

__device__ __forceinline__ unsigned short f2b(float f) {
    unsigned int u = __builtin_bit_cast(unsigned int, f);
    unsigned int r = (u + 0x7FFFu + ((u >> 16) & 1u)) >> 16;
    return (unsigned short)r;
}
__device__ __forceinline__ float sigmoidf_(float x) {
    return 1.0f / (1.0f + __expf(-x));
}
__device__ __forceinline__ float tanhf_(float x) {
    return 1.0f - 2.0f / (__expf(2.0f * x) + 1.0f);
}

// Transpose+convert: W[k][n] fp32 -> Wt[g][n][k] bf16, LDS-tiled 64x64.
__global__ __launch_bounds__(256)
void transpose_w_kernel(const float* __restrict__ w0, const float* __restrict__ w1,
                        const float* __restrict__ w2, const float* __restrict__ w3,
                        unsigned short* __restrict__ dst, int nv) {
    __shared__ unsigned short t[64][65];
    const int gate = blockIdx.z;
    const float* src = (gate == 0) ? w0 : (gate == 1) ? w1 : (gate == 2) ? w2 : w3;
    const int kt = blockIdx.x * 64;
    const int nt = blockIdx.y * 64;
    const int tid = threadIdx.x;
    const int rr = tid >> 6;
    const int cc = tid & 63;
    #pragma unroll
    for (int p = 0; p < 16; ++p) {
        const int row = p * 4 + rr;
        t[cc][row] = f2b(src[(size_t)(kt + row) * NHID + nt + cc]);
    }
    __syncthreads();
    #pragma unroll
    for (int p = 0; p < 16; ++p) {
        const int row = p * 4 + rr;
        dst[((size_t)gate * NHID + nt + row) * nv + kt + cc] = t[row][cc];
    }
}

// x -> bf16, FRAGMENT-MAJOR per timestep:
// xb[t][mg][c][lane][8], lane = koct*16 + row, k = c*32 + koct*8 + e.
__global__ __launch_bounds__(256)
void cvt_x_frag_kernel(const float* __restrict__ x, unsigned short* __restrict__ xb) {
    const int t  = blockIdx.x;        // 0..63
    const int mg = blockIdx.y;        // 0..15
    const int g  = threadIdx.x >> 6;  // 0..3
    const int l  = threadIdx.x & 63;
    const int row = l & 15, ko = l >> 4;
    const float* src = x + (size_t)(mg * 16 + row) * 32768 + t * 512 + ko * 8;
    unsigned short* dst = xb + ((size_t)t * 256 * 512) + ((size_t)mg * 16 * 64 + l) * 8;
    #pragma unroll
    for (int i = 0; i < 4; ++i) {
        const int c = g * 4 + i;
        const float4 v0 = *(const float4*)(src + (size_t)c * 32);
        const float4 v1 = *(const float4*)(src + (size_t)c * 32 + 4);
        ushort4 o0, o1;
        o0.x = f2b(v0.x); o0.y = f2b(v0.y); o0.z = f2b(v0.z); o0.w = f2b(v0.w);
        o1.x = f2b(v1.x); o1.y = f2b(v1.y); o1.z = f2b(v1.z); o1.w = f2b(v1.w);
        *(ushort4*)(dst + (size_t)c * 512)     = o0;
        *(ushort4*)(dst + (size_t)c * 512 + 4) = o1;
    }
}

// Two-level grid barrier (monotone counters, relaxed agent atomics,
// one release fence before arrive + one acquire fence after exit).
__device__ __forceinline__ void grid_sync(unsigned* bar, unsigned gen) {
    __syncthreads();
    if (threadIdx.x == 0) {
        __builtin_amdgcn_fence(__ATOMIC_RELEASE, "agent");
        unsigned* grp  = bar + (blockIdx.x & 7) * 16;
        unsigned* glob = bar + 128;
        unsigned* gctr = bar + 144;
        if (__hip_atomic_fetch_add(grp, 1u, __ATOMIC_RELAXED, __HIP_MEMORY_SCOPE_AGENT)
                == gen * 32u + 31u) {
            if (__hip_atomic_fetch_add(glob, 1u, __ATOMIC_RELAXED, __HIP_MEMORY_SCOPE_AGENT)
                    == gen * 8u + 7u) {
                __hip_atomic_store(gctr, gen + 1u, __ATOMIC_RELAXED, __HIP_MEMORY_SCOPE_AGENT);
            }
        }
        while (__hip_atomic_load(gctr, __ATOMIC_RELAXED, __HIP_MEMORY_SCOPE_AGENT) <= gen) {
            __builtin_amdgcn_s_sleep(2);
        }
        __builtin_amdgcn_fence(__ATOMIC_ACQUIRE, "agent");
    }
    __syncthreads();
}

// Persistent kernel, layer-split, 1024 threads = 16 waves = 8 m-pairs x 2 K-halves.
// layer = (b>>3)&1; lb = (b>>4)*8 + (b&7) in [0,128).
// Block owns hidden [8*lb, 8*lb+8): 32 gate-rows = 2 MFMA row-tiles
// (rt0: F,I ; rt1: C,O), row R: gate=R>>3, hl=R&7.
// LDS: lw[u][rt][lane][8] bf16 (u<32: h-chunk u; u>=32: x-chunk u-32) up to
// 128 KB, then 32 KB reduce buffer red[p][val 0..15][lane].
__global__ __launch_bounds__(1024, 4)
void lstm_persist_kernel(const unsigned short* __restrict__ wt0,   // [4][1024][1536]
                         const unsigned short* __restrict__ wt1,   // [4][1024][2048]
                         const unsigned short* __restrict__ xb,    // frag-major [64][...]
                         const float* __restrict__ bf0, const float* __restrict__ bi0,
                         const float* __restrict__ bc0, const float* __restrict__ bo0,
                         const float* __restrict__ bf1, const float* __restrict__ bi1,
                         const float* __restrict__ bc1, const float* __restrict__ bo1,
                         unsigned short* __restrict__ h0b,   // [2] frag-major
                         unsigned short* __restrict__ h1b,   // [2] frag-major
                         float* __restrict__ h1f,            // [256][1024] fp32 plain
                         unsigned* __restrict__ bar) {
    __shared__ __align__(16) char smem[163840];
    unsigned short* lw  = (unsigned short*)smem;       // up to 128 KB weights
    float*          red = (float*)(smem + 131072);     // 32 KB reduce buffer

    const int tid  = threadIdx.x;
    const int lane = tid & 63;
    const int w    = tid >> 6;     // wave 0..15
    const int p    = w >> 1;       // m-pair 0..7 (m-groups 2p, 2p+1)
    const int kh   = w & 1;        // k-half: 0 = h-recurrent part, 1 = x part
    const int c15  = lane & 15;
    const int kg   = lane >> 4;    // 0..3
    const int b    = blockIdx.x;
    const int layer = (b >> 3) & 1;
    const int lb    = ((b >> 4) << 3) | (b & 7);   // 0..127 within layer

    const unsigned short* wt = layer ? wt1 : wt0;
    const int NV  = layer ? 2048 : 1536;
    const int NCW = NV >> 5;            // 48 or 64 chunks

    // ---- stage this block's 32 gate-rows into LDS, fragment order ----
    #pragma unroll
    for (int i = 0; i < 4; ++i) {
        const int c = w + i * 16;
        if (c < NCW) {
            #pragma unroll
            for (int rt = 0; rt < 2; ++rt) {
                const int R   = rt * 16 + c15;
                const int g   = R >> 3;
                const int hid = 8 * lb + (R & 7);
                const int k   = c * 32 + kg * 8;
                *(bf16x8*)(lw + ((size_t)(c * 2 + rt) * 64 + lane) * 8) =
                    *(const bf16x8*)(wt + ((size_t)g * NHID + hid) * NV + k);
            }
        }
    }

    // biases: biasv[rt][j] for row R = rt*16 + kg*4 + j (used by kh=0 only)
    f32x4 biasv[2];
    {
        const float* bp[4];
        if (layer) { bp[0] = bf1; bp[1] = bi1; bp[2] = bc1; bp[3] = bo1; }
        else       { bp[0] = bf0; bp[1] = bi0; bp[2] = bc0; bp[3] = bo0; }
        #pragma unroll
        for (int rt = 0; rt < 2; ++rt)
            #pragma unroll
            for (int j = 0; j < 4; ++j) {
                const int R = rt * 16 + kg * 4 + j;
                biasv[rt][j] = bp[R >> 3][8 * lb + (R & 7)];
            }
    }
    __syncthreads();

    float cs[4] = {0.f, 0.f, 0.f, 0.f};   // cell state (kh=0 waves only)
    unsigned gen = 0;

    const int rot_h  = (b >> 3) & 31;
    const int rot_xL = layer ? rot_h : ((b >> 4) & 15);
    const bool hiM  = (kg >= 2);

    // h-write position (frag-major), kh=0 waves only (r10 epilogue, w->p)
    const int chw = lb >> 2, kow = lb & 3, eb = (kg & 1) * 4;
    const int mg   = 2 * p + (hiM ? 1 : 0);
    const int mrow = 32 * p + (hiM ? 16 : 0) + c15;
    const size_t hoff = (((size_t)mg * 32 + chw) * 64 + kow * 16 + c15) * 8 + eb;

    float* rw = red + (size_t)p * 16 * 64 + lane;   // [p][val][lane]

    auto step = [&](const int NX, const int rot_x,
                    const unsigned short* bh, const unsigned short* bx,
                    unsigned short* hout, float* hfout) {
        f32x4 a00, a01, a10, a11;    // [rt][mf]
        if (kh == 0) { a00 = biasv[0]; a01 = biasv[0]; a10 = biasv[1]; a11 = biasv[1]; }
        else         { a00 = (f32x4)0.f; a01 = (f32x4)0.f; a10 = (f32x4)0.f; a11 = (f32x4)0.f; }

        // this wave's region: kh=0 -> h chunks [0,32); kh=1 -> x chunks [0,NX)
        const unsigned short* base = kh ? bx : bh;
        const int NC   = kh ? NX : 32;
        const int rot  = kh ? rot_x : rot_h;
        const int msk  = NC - 1;
        const int aoff = kh ? 32 : 0;
        const unsigned short* pb0 = base + ((size_t)(2 * p)     * NC * 64 + lane) * 8;
        const unsigned short* pb1 = base + ((size_t)(2 * p + 1) * NC * 64 + lane) * 8;

        #pragma unroll 8
        for (int i = 0; i < NC; ++i) {
            const int cc = (i + rot) & msk;
            const int ca = aoff + cc;
            const bf16x8 vb0 = *(const bf16x8*)(pb0 + (size_t)cc * 512);
            const bf16x8 vb1 = *(const bf16x8*)(pb1 + (size_t)cc * 512);
            const bf16x8 va0 = *(const bf16x8*)(lw + ((size_t)(ca * 2)     * 64 + lane) * 8);
            const bf16x8 va1 = *(const bf16x8*)(lw + ((size_t)(ca * 2 + 1) * 64 + lane) * 8);
            a00 = __builtin_amdgcn_mfma_f32_16x16x32_bf16(va0, vb0, a00, 0, 0, 0);
            a01 = __builtin_amdgcn_mfma_f32_16x16x32_bf16(va0, vb1, a01, 0, 0, 0);
            a10 = __builtin_amdgcn_mfma_f32_16x16x32_bf16(va1, vb0, a10, 0, 0, 0);
            a11 = __builtin_amdgcn_mfma_f32_16x16x32_bf16(va1, vb1, a11, 0, 0, 0);
        }

        // K-half reduction: kh=1 writes partials (lane-contiguous, no conflicts)
        if (kh == 1) {
            #pragma unroll
            for (int j = 0; j < 4; ++j) {
                rw[(0 * 4 + j) * 64] = a00[j];
                rw[(1 * 4 + j) * 64] = a01[j];
                rw[(2 * 4 + j) * 64] = a10[j];
                rw[(3 * 4 + j) * 64] = a11[j];
            }
        }
        __syncthreads();
        if (kh == 0) {
            #pragma unroll
            for (int j = 0; j < 4; ++j) {
                a00[j] += rw[(0 * 4 + j) * 64];
                a01[j] += rw[(1 * 4 + j) * 64];
                a10[j] += rw[(2 * 4 + j) * 64];
                a11[j] += rw[(3 * 4 + j) * 64];
            }

            // r10's verified epilogue (lane l <-> l^32 gate exchange)
            f32x4 r0, r1;
            #pragma unroll
            for (int j = 0; j < 4; ++j) {
                const float t0 = __shfl_xor(a00[j], 32);
                const float t1 = __shfl_xor(a01[j], 32);
                const float t2 = __shfl_xor(a10[j], 32);
                const float t3 = __shfl_xor(a11[j], 32);
                r0[j] = hiM ? t1 : t0;
                r1[j] = hiM ? t3 : t2;
            }
            const f32x4 own0 = hiM ? a01 : a00;
            const f32x4 own1 = hiM ? a11 : a10;

            ushort4 hb;
            float hv[4];
            #pragma unroll
            for (int j = 0; j < 4; ++j) {
                const float fsv = hiM ? r0[j]   : own0[j];
                const float isv = hiM ? own0[j] : r0[j];
                const float csv = hiM ? r1[j]   : own1[j];
                const float osv = hiM ? own1[j] : r1[j];
                const float fv = sigmoidf_(fsv);
                const float iv = sigmoidf_(isv);
                const float cv = tanhf_(csv);
                const float ov = sigmoidf_(osv);
                const float ccv = fv * cs[j] + iv * cv;
                const float hh  = ov * tanhf_(ccv);
                cs[j] = ccv;
                hv[j] = hh;
            }
            hb.x = f2b(hv[0]); hb.y = f2b(hv[1]); hb.z = f2b(hv[2]); hb.w = f2b(hv[3]);
            *reinterpret_cast<ushort4*>(hout + hoff) = hb;
            if (hfout) {
                float4 hf; hf.x = hv[0]; hf.y = hv[1]; hf.z = hv[2]; hf.w = hv[3];
                *reinterpret_cast<float4*>(hfout + (size_t)mrow * NHID + 8 * lb + eb) = hf;
            }
        }
        // red reuse protected by grid_sync's leading __syncthreads
    };

    // pipeline: interval t: L0-blocks do L0[t], L1-blocks do L1[t-1]; 1 barrier
    for (int t = 0; t <= 64; ++t) {
        if (layer == 0) {
            if (t < 64) {
                step(16, rot_xL,
                     h0b + (size_t)((t + 1) & 1) * HSZE,
                     xb + (size_t)t * 256 * 512,
                     h0b + (size_t)(t & 1) * HSZE, nullptr);
            }
        } else {
            if (t >= 1) {
                const int u = t - 1;
                step(32, rot_xL,
                     h1b + (size_t)((u + 1) & 1) * HSZE,
                     h0b + (size_t)(u & 1) * HSZE,
                     h1b + (size_t)(u & 1) * HSZE,
                     (u == 63) ? h1f : nullptr);
            }
        }
        if (t < 64) {
            grid_sync(bar, gen);
            ++gen;
        }
    }
}

// logits = h1 @ W + b : grid (4 n-blocks, 64 m-blocks), 4 m-rows staged in LDS.
__global__ __launch_bounds__(256)
void classifier_kernel(const float* __restrict__ h, const float* __restrict__ W,
                       const float* __restrict__ b, float* __restrict__ logits) {
    __shared__ float hs[4 * 1024];
    const int tid = threadIdx.x;
    const int m0 = blockIdx.y * 4;
    const int n  = blockIdx.x * 256 + tid;
    #pragma unroll
    for (int i = 0; i < 16; ++i)
        hs[i * 256 + tid] = h[(size_t)m0 * NHID + i * 256 + tid];
    __syncthreads();
    if (n < 1000) {
        float a0 = 0.f, a1 = 0.f, a2 = 0.f, a3 = 0.f;
        #pragma unroll 8
        for (int k = 0; k < NHID; ++k) {
            const float wv = W[(size_t)k * 1000 + n];
            a0 = fmaf(hs[k], wv, a0);
            a1 = fmaf(hs[1024 + k], wv, a1);
            a2 = fmaf(hs[2048 + k], wv, a2);
            a3 = fmaf(hs[3072 + k], wv, a3);
        }
        const float bv = b[n];
        logits[(size_t)(m0 + 0) * 1000 + n] = a0 + bv;
        logits[(size_t)(m0 + 1) * 1000 + n] = a1 + bv;
        logits[(size_t)(m0 + 2) * 1000 + n] = a2 + bv;
        logits[(size_t)(m0 + 3) * 1000 + n] = a3 + bv;
    }
}

__global__ void softmax_kernel(const float* __restrict__ logits, float* __restrict__ pred) {
    __shared__ float red[256];
    const int m = blockIdx.x;
    const int t = threadIdx.x;
    const float* lr = logits + (size_t)m * 1000;
    float mx = -3.4e38f;
    for (int i = t; i < 1000; i += 256) mx = fmaxf(mx, lr[i]);
    red[t] = mx; __syncthreads();
    for (int off = 128; off > 0; off >>= 1) {
        if (t < off) red[t] = fmaxf(red[t], red[t + off]);
        __syncthreads();
    }
    mx = red[0];
    __syncthreads();
    float sm = 0.0f;
    for (int i = t; i < 1000; i += 256) sm += __expf(lr[i] - mx);
    red[t] = sm; __syncthreads();
    for (int off = 128; off > 0; off >>= 1) {
        if (t < off) red[t] += red[t + off];
        __syncthreads();
    }
    const float inv = 1.0f / red[0];
    for (int i = t; i < 1000; i += 256)
        pred[(size_t)m * 1000 + i] = __expf(lr[i] - mx) * inv;
}

extern "C" void kernel_launch(void* const* d_in, const int* in_sizes, int n_in,
                              void* d_out, int out_size, void* d_ws, size_t ws_size,
                              hipStream_t stream) {
    (void)in_sizes; (void)n_in; (void)out_size; (void)ws_size;
    const float* x = (const float*)d_in[0];
    const float* W0[4] = {(const float*)d_in[1], (const float*)d_in[2], (const float*)d_in[3], (const float*)d_in[4]};
    const float* B0[4] = {(const float*)d_in[5], (const float*)d_in[6], (const float*)d_in[7], (const float*)d_in[8]};
    const float* W1[4] = {(const float*)d_in[9], (const float*)d_in[10], (const float*)d_in[11], (const float*)d_in[12]};
    const float* B1[4] = {(const float*)d_in[13], (const float*)d_in[14], (const float*)d_in[15], (const float*)d_in[16]};
    const float* Wc = (const float*)d_in[17];
    const float* bc = (const float*)d_in[18];
    float* out = (float*)d_out;

    char* ws = (char*)d_ws;
    size_t off = 0;
    auto alloc = [&](size_t bytes) -> char* {
        char* p = ws + off;
        off += (bytes + 255) & ~(size_t)255;
        return p;
    };
    unsigned short* wt0 = (unsigned short*)alloc((size_t)4 * NHID * 1536 * 2);
    unsigned short* wt1 = (unsigned short*)alloc((size_t)4 * NHID * 2048 * 2);
    unsigned short* xb  = (unsigned short*)alloc((size_t)NBATCH * 64 * 512 * 2);
    char* hstates = ws + off;
    unsigned short* h0b = (unsigned short*)alloc((size_t)2 * HSZE * 2);
    unsigned short* h1b = (unsigned short*)alloc((size_t)2 * HSZE * 2);
    size_t hstate_bytes = (size_t)((char*)h1b + (size_t)2 * HSZE * 2 - hstates);
    float* h1f = (float*)alloc((size_t)HSZE * 4);
    unsigned* bar = (unsigned*)alloc(1024);

    hipMemsetAsync(hstates, 0, hstate_bytes, stream);
    hipMemsetAsync(bar, 0, 1024, stream);

    transpose_w_kernel<<<dim3(1536 / 64, 16, 4), 256, 0, stream>>>(
        W0[0], W0[1], W0[2], W0[3], wt0, 1536);
    transpose_w_kernel<<<dim3(2048 / 64, 16, 4), 256, 0, stream>>>(
        W1[0], W1[1], W1[2], W1[3], wt1, 2048);
    cvt_x_frag_kernel<<<dim3(64, 16), 256, 0, stream>>>(x, xb);

    lstm_persist_kernel<<<NBLK, 1024, 0, stream>>>(
        wt0, wt1, xb,
        B0[0], B0[1], B0[2], B0[3],
        B1[0], B1[1], B1[2], B1[3],
        h0b, h1b, h1f, bar);

    classifier_kernel<<<dim3(4, 64), 256, 0, stream>>>(h1f, Wc, bc, out);
    softmax_kernel<<<NBATCH, 256, 0, stream>>>(out, out + (size_t)NBATCH * 1000);
}

// Round 17
// 1400.558 us; speedup vs baseline: 1.0846x; 1.0846x over previous
//
#include <hip/hip_runtime.h>
#include <hip/hip_bf16.h>

// ---------------------------------------------------------------------------
// LSTM_37847251812594: 2-layer LSTM (B=256, T=64, n_x=512, n_h=1024) + FC+softmax
// Round 17: decoupled per-layer barriers (r14 step code unchanged).
//   - L0's recurrence is self-contained: 128 L0-blocks barrier among
//     themselves and FREE-RUN ahead; h0 is a 4-slot ring with epoch
//     flow-control (L0 <= 3 intervals ahead of L1's consumption).
//   - L1 blocks barrier among themselves + wait on L0's epoch (satisfied
//     early once pipeline fills). Critical path = L1 barrier + L1 GEMM;
//     L0 stragglers no longer propagate; L2 bursts desynchronize; L1 reads
//     h0 written >=1 interval earlier (settled, no race latency).
//   - everything else identical to r14 (best: 1435): 256 blk x 1024 thr,
//     layer-split, 8 hidden/block, LDS weights, frag-major h/x, shfl
//     epilogue, k-rotation, unroll-8 I$-safe loop.
// ---------------------------------------------------------------------------

typedef short  bf16x8 __attribute__((ext_vector_type(8)));
typedef float  f32x4  __attribute__((ext_vector_type(4)));

#define NHID   1024
#define NBATCH 256
#define NBLK   256
#define HSZE   (NBATCH * NHID)

__device__ __forceinline__ unsigned short f2b(float f) {
    unsigned int u = __builtin_bit_cast(unsigned int, f);
    unsigned int r = (u + 0x7FFFu + ((u >> 16) & 1u)) >> 16;
    return (unsigned short)r;
}
__device__ __forceinline__ float sigmoidf_(float x) {
    return 1.0f / (1.0f + __expf(-x));
}
__device__ __forceinline__ float tanhf_(float x) {
    return 1.0f - 2.0f / (__expf(2.0f * x) + 1.0f);
}

// Transpose+convert: W[k][n] fp32 -> Wt[g][n][k] bf16, LDS-tiled 64x64.
__global__ __launch_bounds__(256)
void transpose_w_kernel(const float* __restrict__ w0, const float* __restrict__ w1,
                        const float* __restrict__ w2, const float* __restrict__ w3,
                        unsigned short* __restrict__ dst, int nv) {
    __shared__ unsigned short t[64][65];
    const int gate = blockIdx.z;
    const float* src = (gate == 0) ? w0 : (gate == 1) ? w1 : (gate == 2) ? w2 : w3;
    const int kt = blockIdx.x * 64;
    const int nt = blockIdx.y * 64;
    const int tid = threadIdx.x;
    const int rr = tid >> 6;
    const int cc = tid & 63;
    #pragma unroll
    for (int p = 0; p < 16; ++p) {
        const int row = p * 4 + rr;
        t[cc][row] = f2b(src[(size_t)(kt + row) * NHID + nt + cc]);
    }
    __syncthreads();
    #pragma unroll
    for (int p = 0; p < 16; ++p) {
        const int row = p * 4 + rr;
        dst[((size_t)gate * NHID + nt + row) * nv + kt + cc] = t[row][cc];
    }
}

// x -> bf16, FRAGMENT-MAJOR per timestep:
// xb[t][mg][c][lane][8], lane = koct*16 + row, k = c*32 + koct*8 + e.
__global__ __launch_bounds__(256)
void cvt_x_frag_kernel(const float* __restrict__ x, unsigned short* __restrict__ xb) {
    const int t  = blockIdx.x;        // 0..63
    const int mg = blockIdx.y;        // 0..15
    const int g  = threadIdx.x >> 6;  // 0..3
    const int l  = threadIdx.x & 63;
    const int row = l & 15, ko = l >> 4;
    const float* src = x + (size_t)(mg * 16 + row) * 32768 + t * 512 + ko * 8;
    unsigned short* dst = xb + ((size_t)t * 256 * 512) + ((size_t)mg * 16 * 64 + l) * 8;
    #pragma unroll
    for (int i = 0; i < 4; ++i) {
        const int c = g * 4 + i;
        const float4 v0 = *(const float4*)(src + (size_t)c * 32);
        const float4 v1 = *(const float4*)(src + (size_t)c * 32 + 4);
        ushort4 o0, o1;
        o0.x = f2b(v0.x); o0.y = f2b(v0.y); o0.z = f2b(v0.z); o0.w = f2b(v0.w);
        o1.x = f2b(v1.x); o1.y = f2b(v1.y); o1.z = f2b(v1.z); o1.w = f2b(v1.w);
        *(ushort4*)(dst + (size_t)c * 512)     = o0;
        *(ushort4*)(dst + (size_t)c * 512 + 4) = o1;
    }
}

// Per-layer group barrier (128 blocks: 4 groups x 32), monotone counters,
// relaxed agent atomics, one release fence before arrive + one acquire after.
// Cross-layer epoch gating:
//   L1 (after its barrier for iter gen): wait gctr_L0 >= gen+1
//     (next iter computes u=gen, reads h0[gen] produced in L0's iter gen).
//   L0 (gen>=2): wait gctr_L1 >= gen-1  (next iter t=gen+1 overwrites the
//     h0 ring slot last read by L1 in iter gen-2; ring depth 4).
// bar layout (uints): L0: grp 0/16/32/48, stage 64, gctr 80;
//                     L1: grp 96/112/128/144, stage 160, gctr 176.
__device__ __forceinline__ void layer_sync(unsigned* bar, unsigned gen,
                                           int layer, int lb) {
    __syncthreads();
    if (threadIdx.x == 0) {
        __builtin_amdgcn_fence(__ATOMIC_RELEASE, "agent");
        unsigned* base = bar + layer * 96;
        unsigned* grp  = base + (lb & 3) * 16;
        unsigned* stg  = base + 64;
        unsigned* gctr = base + 80;
        unsigned* octr = bar + (layer ? 80 : 176);
        if (__hip_atomic_fetch_add(grp, 1u, __ATOMIC_RELAXED, __HIP_MEMORY_SCOPE_AGENT)
                == gen * 32u + 31u) {
            if (__hip_atomic_fetch_add(stg, 1u, __ATOMIC_RELAXED, __HIP_MEMORY_SCOPE_AGENT)
                    == gen * 4u + 3u)
                __hip_atomic_store(gctr, gen + 1u, __ATOMIC_RELAXED, __HIP_MEMORY_SCOPE_AGENT);
        }
        while (__hip_atomic_load(gctr, __ATOMIC_RELAXED, __HIP_MEMORY_SCOPE_AGENT) <= gen)
            __builtin_amdgcn_s_sleep(2);
        if (layer == 1) {
            while (__hip_atomic_load(octr, __ATOMIC_RELAXED, __HIP_MEMORY_SCOPE_AGENT) <= gen)
                __builtin_amdgcn_s_sleep(2);
        } else if (gen >= 2) {
            while (__hip_atomic_load(octr, __ATOMIC_RELAXED, __HIP_MEMORY_SCOPE_AGENT) < gen - 1u)
                __builtin_amdgcn_s_sleep(2);
        }
        __builtin_amdgcn_fence(__ATOMIC_ACQUIRE, "agent");
    }
    __syncthreads();
}

// Persistent kernel, layer-split, 1024 threads = 16 waves (r14 structure).
__global__ __launch_bounds__(1024, 4)
void lstm_persist_kernel(const unsigned short* __restrict__ wt0,   // [4][1024][1536]
                         const unsigned short* __restrict__ wt1,   // [4][1024][2048]
                         const unsigned short* __restrict__ xb,    // frag-major [64][...]
                         const float* __restrict__ bf0, const float* __restrict__ bi0,
                         const float* __restrict__ bc0, const float* __restrict__ bo0,
                         const float* __restrict__ bf1, const float* __restrict__ bi1,
                         const float* __restrict__ bc1, const float* __restrict__ bo1,
                         unsigned short* __restrict__ h0b,   // [4] frag-major ring
                         unsigned short* __restrict__ h1b,   // [2] frag-major
                         float* __restrict__ h1f,            // [256][1024] fp32 plain
                         unsigned* __restrict__ bar) {
    __shared__ __align__(16) unsigned short lw[65536];   // up to 128 KB

    const int tid  = threadIdx.x;
    const int lane = tid & 63;
    const int w    = tid >> 6;     // wave 0..15 -> m-group w (rows 16w..16w+15)
    const int c15  = lane & 15;
    const int kg   = lane >> 4;    // 0..3
    const int b    = blockIdx.x;
    const int layer = (b >> 3) & 1;
    const int lb    = ((b >> 4) << 3) | (b & 7);   // 0..127 within layer

    const unsigned short* wt = layer ? wt1 : wt0;
    const int NV  = layer ? 2048 : 1536;
    const int NCW = NV >> 5;            // 48 or 64 chunks

    // ---- stage this block's 32 gate-rows into LDS, fragment order ----
    #pragma unroll
    for (int i = 0; i < 4; ++i) {
        const int c = w + i * 16;
        if (c < NCW) {
            #pragma unroll
            for (int rt = 0; rt < 2; ++rt) {
                const int R   = rt * 16 + c15;
                const int g   = R >> 3;
                const int hid = 8 * lb + (R & 7);
                const int k   = c * 32 + kg * 8;
                *(bf16x8*)(lw + ((size_t)(c * 2 + rt) * 64 + lane) * 8) =
                    *(const bf16x8*)(wt + ((size_t)g * NHID + hid) * NV + k);
            }
        }
    }

    // biases: biasv[rt][j] for row R = rt*16 + kg*4 + j
    f32x4 biasv[2];
    {
        const float* bp[4];
        if (layer) { bp[0] = bf1; bp[1] = bi1; bp[2] = bc1; bp[3] = bo1; }
        else       { bp[0] = bf0; bp[1] = bi0; bp[2] = bc0; bp[3] = bo0; }
        #pragma unroll
        for (int rt = 0; rt < 2; ++rt)
            #pragma unroll
            for (int j = 0; j < 4; ++j) {
                const int R = rt * 16 + kg * 4 + j;
                biasv[rt][j] = bp[R >> 3][8 * lb + (R & 7)];
            }
    }
    __syncthreads();

    float cs[2] = {0.f, 0.f};   // 2 cells per thread (m = 16w+c15, hid hp..hp+1)
    unsigned gen = 0;

    const int rot_h  = (b >> 3) & 31;
    const int rot_xL = layer ? rot_h : ((b >> 4) & 15);

    // epilogue ownership: lane (kg,c15) handles hidden pair hp = 4*(kg&1)+2*(kg>>1)
    const int hb4  = 4 * (kg & 1);
    const int jsel = (kg >> 1) ? 2 : 0;
    const int hp   = hb4 + jsel;                 // 0,4,2,6 (even)
    const int mrow = 16 * w + c15;
    const int chw  = lb >> 2;                    // h-chunk of hidden 8lb..8lb+7
    const int kow  = lb & 3;                     // k-oct
    const size_t hoff = (((size_t)w * 32 + chw) * 64 + kow * 16 + c15) * 8 + hp;

    auto step = [&](const int NX, const int rot_x,
                    const unsigned short* bh, const unsigned short* bx,
                    unsigned short* hout, float* hfout) {
        f32x4 acc0 = biasv[0], acc1 = biasv[1];   // rt0, rt1 for m-group w
        const unsigned short* ph = bh + ((size_t)w * 32 * 64 + lane) * 8;
        const unsigned short* px = bx + ((size_t)w * NX * 64 + lane) * 8;

        #pragma unroll 8
        for (int i = 0; i < 32; ++i) {
            const int cc = (i + rot_h) & 31;
            const bf16x8 vb  = *(const bf16x8*)(ph + (size_t)cc * 512);
            const bf16x8 va0 = *(const bf16x8*)(lw + ((size_t)(cc * 2)     * 64 + lane) * 8);
            const bf16x8 va1 = *(const bf16x8*)(lw + ((size_t)(cc * 2 + 1) * 64 + lane) * 8);
            acc0 = __builtin_amdgcn_mfma_f32_16x16x32_bf16(va0, vb, acc0, 0, 0, 0);
            acc1 = __builtin_amdgcn_mfma_f32_16x16x32_bf16(va1, vb, acc1, 0, 0, 0);
        }
        #pragma unroll 8
        for (int i = 0; i < NX; ++i) {
            const int cc = (i + rot_x) & (NX - 1);
            const bf16x8 vb  = *(const bf16x8*)(px + (size_t)cc * 512);
            const bf16x8 va0 = *(const bf16x8*)(lw + ((size_t)((32 + cc) * 2)     * 64 + lane) * 8);
            const bf16x8 va1 = *(const bf16x8*)(lw + ((size_t)((32 + cc) * 2 + 1) * 64 + lane) * 8);
            acc0 = __builtin_amdgcn_mfma_f32_16x16x32_bf16(va0, vb, acc0, 0, 0, 0);
            acc1 = __builtin_amdgcn_mfma_f32_16x16x32_bf16(va1, vb, acc1, 0, 0, 0);
        }

        // gate exchange: lane kg holds rows 4kg..4kg+3 of rt0 (F:kg<2 / I:kg>=2)
        // and rt1 (C / O). Partner kg^2 supplies the complementary pair.
        f32x4 racc0, racc1;
        #pragma unroll
        for (int j = 0; j < 4; ++j) {
            racc0[j] = __shfl_xor(acc0[j], 32);
            racc1[j] = __shfl_xor(acc1[j], 32);
        }

        float hv[2];
        #pragma unroll
        for (int jj = 0; jj < 2; ++jj) {
            const int j = jsel + jj;
            float fsv, isv, csv, osv;
            if (kg < 2) { fsv = acc0[j];  isv = racc0[j]; csv = acc1[j];  osv = racc1[j]; }
            else        { fsv = racc0[j]; isv = acc0[j];  csv = racc1[j]; osv = acc1[j];  }
            const float fv = sigmoidf_(fsv);
            const float iv = sigmoidf_(isv);
            const float cv = tanhf_(csv);
            const float ov = sigmoidf_(osv);
            const float ccv = fv * cs[jj] + iv * cv;
            const float hh  = ov * tanhf_(ccv);
            cs[jj] = ccv;
            hv[jj] = hh;
        }
        const unsigned hbp = (unsigned)f2b(hv[0]) | ((unsigned)f2b(hv[1]) << 16);
        *reinterpret_cast<unsigned*>(hout + hoff) = hbp;
        if (hfout) {
            float2 hf; hf.x = hv[0]; hf.y = hv[1];
            *reinterpret_cast<float2*>(hfout + (size_t)mrow * NHID + 8 * lb + hp) = hf;
        }
    };

    // pipeline: iter t: L0-blocks do L0[t] (h0 ring slot t&3),
    //                   L1-blocks do L1[t-1]; per-layer barriers only.
    for (int t = 0; t <= 64; ++t) {
        if (layer == 0) {
            if (t < 64) {
                step(16, rot_xL,
                     h0b + (size_t)((t + 3) & 3) * HSZE,   // h0[t-1]
                     xb + (size_t)t * 256 * 512,
                     h0b + (size_t)(t & 3) * HSZE, nullptr);
            }
        } else {
            if (t >= 1) {
                const int u = t - 1;
                step(32, rot_xL,
                     h1b + (size_t)((u + 1) & 1) * HSZE,
                     h0b + (size_t)(u & 3) * HSZE,
                     h1b + (size_t)(u & 1) * HSZE,
                     (u == 63) ? h1f : nullptr);
            }
        }
        if (t < 64) {
            layer_sync(bar, gen, layer, lb);
            ++gen;
        }
    }
}

// logits = h1 @ W + b : grid (4 n-blocks, 64 m-blocks), 4 m-rows staged in LDS.
__global__ __launch_bounds__(256)
void classifier_kernel(const float* __restrict__ h, const float* __restrict__ W,
                       const float* __restrict__ b, float* __restrict__ logits) {
    __shared__ float hs[4 * 1024];
    const int tid = threadIdx.x;
    const int m0 = blockIdx.y * 4;
    const int n  = blockIdx.x * 256 + tid;
    #pragma unroll
    for (int i = 0; i < 16; ++i)
        hs[i * 256 + tid] = h[(size_t)m0 * NHID + i * 256 + tid];
    __syncthreads();
    if (n < 1000) {
        float a0 = 0.f, a1 = 0.f, a2 = 0.f, a3 = 0.f;
        #pragma unroll 8
        for (int k = 0; k < NHID; ++k) {
            const float wv = W[(size_t)k * 1000 + n];
            a0 = fmaf(hs[k], wv, a0);
            a1 = fmaf(hs[1024 + k], wv, a1);
            a2 = fmaf(hs[2048 + k], wv, a2);
            a3 = fmaf(hs[3072 + k], wv, a3);
        }
        const float bv = b[n];
        logits[(size_t)(m0 + 0) * 1000 + n] = a0 + bv;
        logits[(size_t)(m0 + 1) * 1000 + n] = a1 + bv;
        logits[(size_t)(m0 + 2) * 1000 + n] = a2 + bv;
        logits[(size_t)(m0 + 3) * 1000 + n] = a3 + bv;
    }
}

__global__ void softmax_kernel(const float* __restrict__ logits, float* __restrict__ pred) {
    __shared__ float red[256];
    const int m = blockIdx.x;
    const int t = threadIdx.x;
    const float* lr = logits + (size_t)m * 1000;
    float mx = -3.4e38f;
    for (int i = t; i < 1000; i += 256) mx = fmaxf(mx, lr[i]);
    red[t] = mx; __syncthreads();
    for (int off = 128; off > 0; off >>= 1) {
        if (t < off) red[t] = fmaxf(red[t], red[t + off]);
        __syncthreads();
    }
    mx = red[0];
    __syncthreads();
    float sm = 0.0f;
    for (int i = t; i < 1000; i += 256) sm += __expf(lr[i] - mx);
    red[t] = sm; __syncthreads();
    for (int off = 128; off > 0; off >>= 1) {
        if (t < off) red[t] += red[t + off];
        __syncthreads();
    }
    const float inv = 1.0f / red[0];
    for (int i = t; i < 1000; i += 256)
        pred[(size_t)m * 1000 + i] = __expf(lr[i] - mx) * inv;
}

extern "C" void kernel_launch(void* const* d_in, const int* in_sizes, int n_in,
                              void* d_out, int out_size, void* d_ws, size_t ws_size,
                              hipStream_t stream) {
    (void)in_sizes; (void)n_in; (void)out_size; (void)ws_size;
    const float* x = (const float*)d_in[0];
    const float* W0[4] = {(const float*)d_in[1], (const float*)d_in[2], (const float*)d_in[3], (const float*)d_in[4]};
    const float* B0[4] = {(const float*)d_in[5], (const float*)d_in[6], (const float*)d_in[7], (const float*)d_in[8]};
    const float* W1[4] = {(const float*)d_in[9], (const float*)d_in[10], (const float*)d_in[11], (const float*)d_in[12]};
    const float* B1[4] = {(const float*)d_in[13], (const float*)d_in[14], (const float*)d_in[15], (const float*)d_in[16]};
    const float* Wc = (const float*)d_in[17];
    const float* bc = (const float*)d_in[18];
    float* out = (float*)d_out;

    char* ws = (char*)d_ws;
    size_t off = 0;
    auto alloc = [&](size_t bytes) -> char* {
        char* p = ws + off;
        off += (bytes + 255) & ~(size_t)255;
        return p;
    };
    unsigned short* wt0 = (unsigned short*)alloc((size_t)4 * NHID * 1536 * 2);
    unsigned short* wt1 = (unsigned short*)alloc((size_t)4 * NHID * 2048 * 2);
    unsigned short* xb  = (unsigned short*)alloc((size_t)NBATCH * 64 * 512 * 2);
    char* hstates = ws + off;
    unsigned short* h0b = (unsigned short*)alloc((size_t)4 * HSZE * 2);   // 4-slot ring
    unsigned short* h1b = (unsigned short*)alloc((size_t)2 * HSZE * 2);
    size_t hstate_bytes = (size_t)((char*)h1b + (size_t)2 * HSZE * 2 - hstates);
    float* h1f = (float*)alloc((size_t)HSZE * 4);
    unsigned* bar = (unsigned*)alloc(1024);

    hipMemsetAsync(hstates, 0, hstate_bytes, stream);
    hipMemsetAsync(bar, 0, 1024, stream);

    transpose_w_kernel<<<dim3(1536 / 64, 16, 4), 256, 0, stream>>>(
        W0[0], W0[1], W0[2], W0[3], wt0, 1536);
    transpose_w_kernel<<<dim3(2048 / 64, 16, 4), 256, 0, stream>>>(
        W1[0], W1[1], W1[2], W1[3], wt1, 2048);
    cvt_x_frag_kernel<<<dim3(64, 16), 256, 0, stream>>>(x, xb);

    lstm_persist_kernel<<<NBLK, 1024, 0, stream>>>(
        wt0, wt1, xb,
        B0[0], B0[1], B0[2], B0[3],
        B1[0], B1[1], B1[2], B1[3],
        h0b, h1b, h1f, bar);

    classifier_kernel<<<dim3(4, 64), 256, 0, stream>>>(h1f, Wc, bc, out);
    softmax_kernel<<<NBATCH, 256, 0, stream>>>(out, out + (size_t)NBATCH * 1000);
}